// Round 18
// baseline (96.315 us; speedup 1.0000x reference)
//
#include <hip/hip_runtime.h>

#define DIM 64
#define NCODE 1024

typedef __attribute__((ext_vector_type(8))) short bf16x8;
typedef __attribute__((ext_vector_type(4))) float f32x4;

// ---- small ws (8.3 KB) ----
#define WSO_SLOTS 0        // float[256] loss slots
#define WSO_COUNT 4100     // int
#define WSO_MAX4  4112     // float[4]
#define WSO_CBN   4160     // float[1024]

// ---- big scratch in d_out's out_xq region ----
// cbt @0 (262144 B) | cbT @262144 (262144 B) | list @524288 (131072 B, reused as hist partials)
// Order: prep -> mfma -> refine -> hist -> freq -> E1 -> E2 -> loss.

__device__ __forceinline__ unsigned short f2bf(float f) {
    unsigned u = __float_as_uint(f);
    unsigned r = (u + 0x7FFFu + ((u >> 16) & 1u)) >> 16;   // RNE
    return (unsigned short)r;
}

__device__ __forceinline__ void gload16(const void* g, void* l) {
    __builtin_amdgcn_global_load_lds(
        (const __attribute__((address_space(1))) unsigned int*)g,
        (__attribute__((address_space(3))) unsigned int*)l, 16, 0, 0);
}

// ---- kernel 0: prep (4 x 256) ----
__global__ __launch_bounds__(256) void vq_prep(const float* __restrict__ cb,
                                               char* __restrict__ ws,
                                               char* __restrict__ cbt,
                                               float* __restrict__ cbT) {
    __shared__ float red[256];
    const int t = threadIdx.x;
    const int k = blockIdx.x * 256 + t;

    float cv[64];
#pragma unroll
    for (int d = 0; d < DIM; ++d) cv[d] = cb[d * NCODE + k];

    float s = 0.f;
#pragma unroll
    for (int d = 0; d < DIM; ++d) s = fmaf(cv[d], cv[d], s);

    ((float*)(ws + WSO_CBN))[k] = s;
    if (blockIdx.x == 0) ((float*)(ws + WSO_SLOTS))[t] = 0.f;

    unsigned short hi[64], lo[64];
#pragma unroll
    for (int d = 0; d < DIM; ++d) {
        unsigned short h = f2bf(cv[d]);
        float hf = __uint_as_float(((unsigned)h) << 16);
        hi[d] = h;
        lo[d] = f2bf(cv[d] - hf);
    }

    const int c = k >> 6, cc = k & 63, wv = cc >> 4, col = cc & 15;
    char* base = cbt + (size_t)(c * 4 + wv) * 4096;
#pragma unroll
    for (int g = 0; g < 4; ++g) {
        bf16x8 h0v, h1v, l0v, l1v;
#pragma unroll
        for (int e = 0; e < 8; ++e) {
            h0v[e] = (short)hi[g * 8 + e];
            h1v[e] = (short)hi[32 + g * 8 + e];
            l0v[e] = (short)lo[g * 8 + e];
            l1v[e] = (short)lo[32 + g * 8 + e];
        }
        const int off = (g * 16 + col) * 16;
        *(bf16x8*)(base + off)        = h0v;
        *(bf16x8*)(base + 1024 + off) = h1v;
        *(bf16x8*)(base + 2048 + off) = l0v;
        *(bf16x8*)(base + 3072 + off) = l1v;
    }

#pragma unroll
    for (int j = 0; j < 16; ++j) {
        float4 v = {cv[4 * j], cv[4 * j + 1], cv[4 * j + 2], cv[4 * j + 3]};
        *(float4*)(cbT + (size_t)k * 64 + 4 * j) = v;
    }

    red[t] = s;
    __syncthreads();
    for (int m = 128; m > 0; m >>= 1) {
        if (t < m) red[t] = fmaxf(red[t], red[t + m]);
        __syncthreads();
    }
    if (t == 0) {
        ((float*)(ws + WSO_MAX4))[blockIdx.x] = red[0];
        if (blockIdx.x == 0) *(int*)(ws + WSO_COUNT) = 0;
    }
}

// ---- kernel 1: MFMA distances (R16/R17 verbatim) ----
__global__ __launch_bounds__(256, 3) void vq_mfma(const float* __restrict__ x,
                                                  const char* __restrict__ cbt,
                                                  char* __restrict__ ws,
                                                  unsigned short* __restrict__ list,
                                                  float* __restrict__ out_idx) {
    __shared__ __align__(16) char sm[20736];
    char*  bX    = sm;
    float* cbn_s = (float*)(sm + 16384);
    float* xx_s  = (float*)(sm + 20480);
    float* R1    = (float*)sm;
    float* R2v   = R1 + 128;
    int*   RIv   = (int*)(R2v + 128);
    int*   cntL  = (int*)(sm + 8192);

    const int t = threadIdx.x, w = t >> 6, lane = t & 63;
    const int rh = w & 1, ct = w >> 1;
    const int r0 = blockIdx.x * 64;

    const float* mb4 = (const float*)(ws + WSO_MAX4);
    const float maxcbn = fmaxf(fmaxf(mb4[0], mb4[1]), fmaxf(mb4[2], mb4[3]));

    gload16((const char*)(ws + WSO_CBN) + ((size_t)w * 64 + lane) * 16, (char*)cbn_s + w * 1024);

    {
        const int row = t >> 2, q = t & 3;
        const float4* xp = (const float4*)(x + (size_t)(r0 + row) * DIM + q * 16);
        float4 v0 = xp[0], v1 = xp[1], v2 = xp[2], v3 = xp[3];
        float p = 0.f;
        p = fmaf(v0.x, v0.x, p); p = fmaf(v0.y, v0.y, p); p = fmaf(v0.z, v0.z, p); p = fmaf(v0.w, v0.w, p);
        p = fmaf(v1.x, v1.x, p); p = fmaf(v1.y, v1.y, p); p = fmaf(v1.z, v1.z, p); p = fmaf(v1.w, v1.w, p);
        p = fmaf(v2.x, v2.x, p); p = fmaf(v2.y, v2.y, p); p = fmaf(v2.z, v2.z, p); p = fmaf(v2.w, v2.w, p);
        p = fmaf(v3.x, v3.x, p); p = fmaf(v3.y, v3.y, p); p = fmaf(v3.z, v3.z, p); p = fmaf(v3.w, v3.w, p);
        p += __shfl_xor(p, 1);
        p += __shfl_xor(p, 2);
        if (q == 0) xx_s[row] = p;

        float hv[16] = {v0.x, v0.y, v0.z, v0.w, v1.x, v1.y, v1.z, v1.w,
                        v2.x, v2.y, v2.z, v2.w, v3.x, v3.y, v3.z, v3.w};
        bf16x8 ph[2], pl[2];
#pragma unroll
        for (int h = 0; h < 2; ++h)
#pragma unroll
            for (int e = 0; e < 8; ++e) {
                float v = hv[h * 8 + e];
                unsigned short hb = f2bf(v);
                float hf = __uint_as_float(((unsigned)hb) << 16);
                ph[h][e] = (short)hb;
                pl[h][e] = (short)f2bf(v - hf);
            }
        const int sw = row & 7;
        char* base = bX + row * 256;
#pragma unroll
        for (int h = 0; h < 2; ++h) {
            int s3 = (2 * q + h) ^ sw;
            *(bf16x8*)(base + (s3 & 7) * 16)        = ph[h];
            *(bf16x8*)(base + (8 | (s3 & 7)) * 16)  = pl[h];
        }
    }
    __syncthreads();

    bf16x8 afh[2][2], afl[2][2];
#pragma unroll
    for (int rt = 0; rt < 2; ++rt)
#pragma unroll
        for (int kt = 0; kt < 2; ++kt) {
            int row = rh * 32 + rt * 16 + (lane & 15);
            int s3 = ((kt * 4 + (lane >> 4)) ^ (row & 7)) & 7;
            afh[rt][kt] = *(const bf16x8*)(bX + row * 256 + s3 * 16);
            afl[rt][kt] = *(const bf16x8*)(bX + row * 256 + (8 | s3) * 16);
        }

    const int cl = ct * 16 + (lane & 15);

    float m1[8], m2[8];
    int   mi[8];
#pragma unroll
    for (int s = 0; s < 8; ++s) { m1[s] = 3.4e38f; m2[s] = 3.4e38f; mi[s] = 0; }

    const char* pc = cbt + (size_t)ct * 4096 + (size_t)lane * 16;

    bf16x8 bh0 = *(const bf16x8*)(pc);
    bf16x8 bh1 = *(const bf16x8*)(pc + 1024);
    bf16x8 bl0 = *(const bf16x8*)(pc + 2048);
    bf16x8 bl1 = *(const bf16x8*)(pc + 3072);

#pragma unroll 1
    for (int c2 = 0; c2 < 32; ++c2) {
        const char* np = pc + 8192;
        bf16x8 nh0 = *(const bf16x8*)(np);
        bf16x8 nh1 = *(const bf16x8*)(np + 1024);
        bf16x8 nl0 = *(const bf16x8*)(np + 2048);
        bf16x8 nl1 = *(const bf16x8*)(np + 3072);

        const int kg = c2 * 32 + cl;
        const float cbnv = cbn_s[kg];

#pragma unroll
        for (int rt = 0; rt < 2; ++rt) {
            f32x4 z = {0.f, 0.f, 0.f, 0.f};
            z = __builtin_amdgcn_mfma_f32_16x16x32_bf16(afh[rt][0], bh0, z, 0, 0, 0);
            z = __builtin_amdgcn_mfma_f32_16x16x32_bf16(afh[rt][1], bh1, z, 0, 0, 0);
            z = __builtin_amdgcn_mfma_f32_16x16x32_bf16(afl[rt][0], bh0, z, 0, 0, 0);
            z = __builtin_amdgcn_mfma_f32_16x16x32_bf16(afl[rt][1], bh1, z, 0, 0, 0);
            z = __builtin_amdgcn_mfma_f32_16x16x32_bf16(afh[rt][0], bl0, z, 0, 0, 0);
            z = __builtin_amdgcn_mfma_f32_16x16x32_bf16(afh[rt][1], bl1, z, 0, 0, 0);
#pragma unroll
            for (int v = 0; v < 4; ++v) {
                const int s = rt * 4 + v;
                float dd = fmaf(-2.f, z[v], cbnv);
                bool lt = dd < m1[s];
                m2[s] = fminf(m2[s], fmaxf(m1[s], dd));
                m1[s] = fminf(m1[s], dd);
                mi[s] = lt ? kg : mi[s];
            }
        }
        pc = np;
        bh0 = nh0; bh1 = nh1; bl0 = nl0; bl1 = nl1;
    }

#pragma unroll
    for (int m = 1; m <= 8; m <<= 1) {
#pragma unroll
        for (int s = 0; s < 8; ++s) {
            float o1 = __shfl_xor(m1[s], m);
            float o2 = __shfl_xor(m2[s], m);
            int   oi = __shfl_xor(mi[s], m);
            float nm2 = fminf(fminf(m2[s], o2), fmaxf(m1[s], o1));
            bool tk = (o1 < m1[s]) || (o1 == m1[s] && oi < mi[s]);
            m1[s] = fminf(m1[s], o1);
            mi[s] = tk ? oi : mi[s];
            m2[s] = nm2;
        }
    }
    __syncthreads();
    if ((lane & 15) == 0) {
        const int gq = lane >> 4;
#pragma unroll
        for (int s = 0; s < 8; ++s) {
            const int row = rh * 32 + (s >> 2) * 16 + gq * 4 + (s & 3);
            R1[row * 2 + ct]  = m1[s];
            R2v[row * 2 + ct] = m2[s];
            RIv[row * 2 + ct] = mi[s];
        }
    }
    __syncthreads();

    bool flag = false;
    int  rr = 0;
    if (t < 128) {
        const int row = t >> 1, q = t & 1;
        float a1 = R1[row * 2 + q];
        float A2 = R2v[row * 2 + q];
        int   ai = RIv[row * 2 + q];
        {
            float o1 = __shfl_xor(a1, 1);
            float o2 = __shfl_xor(A2, 1);
            int   oi = __shfl_xor(ai, 1);
            float nm2 = fminf(fminf(A2, o2), fmaxf(a1, o1));
            bool tk = (o1 < a1) || (o1 == a1 && oi < ai);
            a1 = fminf(a1, o1);
            ai = tk ? oi : ai;
            A2 = nm2;
        }
        if (q == 0) {
            const int r = r0 + row;
            out_idx[r] = (float)ai;
            const float Bv = 1.5e-4f * sqrtf(xx_s[row] * maxcbn) + 2e-3f;
            flag = (A2 - a1 <= 2.f * Bv);
            rr = r;
        }
    }
    unsigned long long mk = __ballot(flag);
    const int wcnt = __popcll(mk);
    if (lane == 0) cntL[w] = wcnt;
    __syncthreads();
    if (t == 0) {
        int c0 = cntL[0], c1 = cntL[1], c2 = cntL[2], c3 = cntL[3];
        int tot = c0 + c1 + c2 + c3;
        int base = 0;
        if (tot) base = atomicAdd((int*)(ws + WSO_COUNT), tot);
        cntL[0] = base;
        cntL[1] = base + c0;
        cntL[2] = base + c0 + c1;
        cntL[3] = base + c0 + c1 + c2;
    }
    __syncthreads();
    if (flag) {
        const int off = __popcll(mk & ((1ull << lane) - 1ull));
        list[cntL[w] + off] = (unsigned short)rr;
    }
}

// ---- kernel 2: refine v5 — 4 rows/wave, x via LDS broadcast, coalesced d-major cb ----
// Block: 16 list-rows staged in LDS; wave w scans all 1024 codes for rows 4w..4w+3.
// Codebook L2 traffic cut 4x vs v3 (one stream per 4 rows instead of per row).
__global__ __launch_bounds__(256) void vq_refine(const float* __restrict__ x,
                                                 const float* __restrict__ cb,
                                                 const char* __restrict__ ws,
                                                 const unsigned short* __restrict__ list,
                                                 float* __restrict__ out_idx) {
    const int N = *(const int*)(ws + WSO_COUNT);
    if ((int)blockIdx.x * 16 >= N) return;
    __shared__ float rx[16][64];
    __shared__ float xxs[16];
    const float* cbn = (const float*)(ws + WSO_CBN);
    const int t = threadIdx.x, w = t >> 6, lane = t & 63;

    // stage 16 rows (4 floats/thread, coalesced within each gathered row)
    {
        const int rowi = t >> 4;
        const int ii = blockIdx.x * 16 + rowi;
        const int r = (ii < N) ? (int)list[ii] : (int)list[0];
        const int d4 = (t & 15) * 4;
        *(float4*)&rx[rowi][d4] = *(const float4*)(x + (size_t)r * DIM + d4);
    }
    __syncthreads();
    if (t < 16) {
        float s = 0.f;
        for (int d = 0; d < 64; ++d) s = fmaf(rx[t][d], rx[t][d], s);
        xxs[t] = s;
    }
    __syncthreads();

    const int rbase = w * 4;
    const float xx0 = xxs[rbase + 0], xx1 = xxs[rbase + 1];
    const float xx2 = xxs[rbase + 2], xx3 = xxs[rbase + 3];

    float bd[4] = {3.4e38f, 3.4e38f, 3.4e38f, 3.4e38f};
    int   bk[4] = {0, 0, 0, 0};

#pragma unroll 1
    for (int kb = 0; kb < NCODE; kb += 64) {
        // 2 chains per row: chain a = dims {0,1 mod 4}, chain b = dims {2,3 mod 4}
        float a0 = 0.f, b0 = 0.f, a1 = 0.f, b1 = 0.f;
        float a2 = 0.f, b2 = 0.f, a3 = 0.f, b3 = 0.f;
        const float* cp = cb + kb + lane;
#pragma unroll
        for (int j = 0; j < 16; ++j) {
            const float cv0 = cp[(4 * j + 0) * NCODE];
            const float cv1 = cp[(4 * j + 1) * NCODE];
            const float cv2 = cp[(4 * j + 2) * NCODE];
            const float cv3 = cp[(4 * j + 3) * NCODE];
            const float4 x0 = *(const float4*)&rx[rbase + 0][4 * j];
            const float4 x1 = *(const float4*)&rx[rbase + 1][4 * j];
            const float4 x2 = *(const float4*)&rx[rbase + 2][4 * j];
            const float4 x3 = *(const float4*)&rx[rbase + 3][4 * j];
            a0 = fmaf(cv0, x0.x, a0); a0 = fmaf(cv1, x0.y, a0);
            b0 = fmaf(cv2, x0.z, b0); b0 = fmaf(cv3, x0.w, b0);
            a1 = fmaf(cv0, x1.x, a1); a1 = fmaf(cv1, x1.y, a1);
            b1 = fmaf(cv2, x1.z, b1); b1 = fmaf(cv3, x1.w, b1);
            a2 = fmaf(cv0, x2.x, a2); a2 = fmaf(cv1, x2.y, a2);
            b2 = fmaf(cv2, x2.z, b2); b2 = fmaf(cv3, x2.w, b2);
            a3 = fmaf(cv0, x3.x, a3); a3 = fmaf(cv1, x3.y, a3);
            b3 = fmaf(cv2, x3.z, b3); b3 = fmaf(cv3, x3.w, b3);
        }
        const float cbnv = cbn[kb + lane];
        const int k = kb + lane;
        const float d0 = fmaf(-2.f, a0 + b0, xx0) + cbnv;
        const float d1 = fmaf(-2.f, a1 + b1, xx1) + cbnv;
        const float d2 = fmaf(-2.f, a2 + b2, xx2) + cbnv;
        const float d3 = fmaf(-2.f, a3 + b3, xx3) + cbnv;
        if (d0 < bd[0]) { bd[0] = d0; bk[0] = k; }   // per-lane k ascending
        if (d1 < bd[1]) { bd[1] = d1; bk[1] = k; }
        if (d2 < bd[2]) { bd[2] = d2; bk[2] = k; }
        if (d3 < bd[3]) { bd[3] = d3; bk[3] = k; }
    }

#pragma unroll
    for (int m = 1; m < 64; m <<= 1) {
#pragma unroll
        for (int rr = 0; rr < 4; ++rr) {
            float od = __shfl_xor(bd[rr], m);
            int   ok = __shfl_xor(bk[rr], m);
            if (od < bd[rr] || (od == bd[rr] && ok < bk[rr])) { bd[rr] = od; bk[rr] = ok; }
        }
    }
    if (lane == 0) {
#pragma unroll
        for (int rr = 0; rr < 4; ++rr) {
            const int ii = blockIdx.x * 16 + rbase + rr;
            if (ii < N) out_idx[(int)list[ii]] = (float)bk[rr];
        }
    }
}

// ---- kernel 2b: atomic-free histogram (R17 verbatim) ----
__global__ __launch_bounds__(256) void vq_hist(const float* __restrict__ idx_f,
                                               float* __restrict__ partials) {
    __shared__ int lh[1024];
    const int t = threadIdx.x;
    lh[t] = 0; lh[t + 256] = 0; lh[t + 512] = 0; lh[t + 768] = 0;
    __syncthreads();
    const int base = blockIdx.x * 2048;
#pragma unroll
    for (int i = 0; i < 8; ++i) {
        int k = (int)idx_f[base + i * 256 + t];
        atomicAdd(&lh[k], 1);
    }
    __syncthreads();
    float* P = partials + (size_t)blockIdx.x * 1024;
    P[t]       = (float)lh[t];
    P[t + 256] = (float)lh[t + 256];
    P[t + 512] = (float)lh[t + 512];
    P[t + 768] = (float)lh[t + 768];
}

// ---- kernel 2c: freq (R17 verbatim) ----
__global__ __launch_bounds__(256) void vq_freq(const float* __restrict__ cf,
                                               const float* __restrict__ partials,
                                               float* __restrict__ out_freq) {
    const int k = blockIdx.x * 256 + threadIdx.x;
    float s = 0.f;
#pragma unroll
    for (int b = 0; b < 32; ++b) s += partials[(size_t)b * 1024 + k];
    out_freq[k] = 0.95f * cf[k] + 0.05f * s;
}

// ---- kernel 3a: epilogue E1 (R17 verbatim) ----
__global__ __launch_bounds__(256) void vq_epi_main(const float* __restrict__ x,
                                                   const float* __restrict__ cbT,
                                                   const float* __restrict__ idx_f,
                                                   float* __restrict__ out_xq,
                                                   char* __restrict__ ws) {
    __shared__ float lred[4];
    const int t = threadIdx.x;
    const int r_lin = blockIdx.x * 32 + (t >> 3);
    const int r = (r_lin < 1024) ? r_lin : r_lin + 1024;
    const int q8 = t & 7;
    const int k = (int)idx_f[r];

    const float4* cp = (const float4*)(cbT + (size_t)k * 64 + q8 * 8);
    const float4* xp = (const float4*)(x + (size_t)r * DIM + q8 * 8);
    float4* op = (float4*)(out_xq + (size_t)r * DIM + q8 * 8);

    float4 c0 = cp[0], c1 = cp[1];
    float4 x0 = xp[0], x1 = xp[1];
    float e0 = c0.x - x0.x, e1 = c0.y - x0.y, e2 = c0.z - x0.z, e3 = c0.w - x0.w;
    float e4 = c1.x - x1.x, e5 = c1.y - x1.y, e6 = c1.z - x1.z, e7 = c1.w - x1.w;
    float4 o0, o1;
    o0.x = x0.x + e0; o0.y = x0.y + e1; o0.z = x0.z + e2; o0.w = x0.w + e3;
    o1.x = x1.x + e4; o1.y = x1.y + e5; o1.z = x1.z + e6; o1.w = x1.w + e7;
    op[0] = o0; op[1] = o1;

    float lsum = 0.f;
    lsum = fmaf(e0, e0, lsum); lsum = fmaf(e1, e1, lsum);
    lsum = fmaf(e2, e2, lsum); lsum = fmaf(e3, e3, lsum);
    lsum = fmaf(e4, e4, lsum); lsum = fmaf(e5, e5, lsum);
    lsum = fmaf(e6, e6, lsum); lsum = fmaf(e7, e7, lsum);

#pragma unroll
    for (int off = 1; off < 64; off <<= 1) lsum += __shfl_xor(lsum, off);
    if ((t & 63) == 0) lred[t >> 6] = lsum;
    __syncthreads();
    if (t == 0)
        atomicAdd((float*)(ws + WSO_SLOTS) + (blockIdx.x & 255),
                  (lred[0] + lred[1]) + (lred[2] + lred[3]));
}

// ---- kernel 3b: epilogue E2 (R17 verbatim) ----
__global__ __launch_bounds__(256) void vq_epi_tail(const float* __restrict__ x,
                                                   const float* __restrict__ cb,
                                                   const float* __restrict__ idx_f,
                                                   float* __restrict__ out_xq,
                                                   char* __restrict__ ws) {
    __shared__ float lred[4];
    const int t = threadIdx.x;
    const int row = 1024 + blockIdx.x * 64 + (t >> 2), q = t & 3;
    const int k = (int)idx_f[row];
    const float4* xp = (const float4*)(x + (size_t)row * DIM + q * 16);
    float4* op = (float4*)(out_xq + (size_t)row * DIM + q * 16);
    float lsum = 0.f;
#pragma unroll
    for (int j = 0; j < 4; ++j) {
        float4 xv = xp[j];
        const int d0 = q * 16 + 4 * j;
        float q0 = cb[(d0 + 0) * NCODE + k];
        float q1 = cb[(d0 + 1) * NCODE + k];
        float q2 = cb[(d0 + 2) * NCODE + k];
        float q3 = cb[(d0 + 3) * NCODE + k];
        float e0 = q0 - xv.x, e1 = q1 - xv.y, e2 = q2 - xv.z, e3 = q3 - xv.w;
        float4 o;
        o.x = xv.x + e0; o.y = xv.y + e1; o.z = xv.z + e2; o.w = xv.w + e3;
        op[j] = o;
        lsum = fmaf(e0, e0, lsum); lsum = fmaf(e1, e1, lsum);
        lsum = fmaf(e2, e2, lsum); lsum = fmaf(e3, e3, lsum);
    }
#pragma unroll
    for (int off = 1; off < 64; off <<= 1) lsum += __shfl_xor(lsum, off);
    if ((t & 63) == 0) lred[t >> 6] = lsum;
    __syncthreads();
    if (t == 0)
        atomicAdd((float*)(ws + WSO_SLOTS) + blockIdx.x,
                  (lred[0] + lred[1]) + (lred[2] + lred[3]));
}

// ---- kernel 4: loss finalize (R17 verbatim) ----
__global__ __launch_bounds__(256) void vq_loss(const char* __restrict__ ws,
                                               float* __restrict__ out_loss) {
    __shared__ float red[256];
    const int t = threadIdx.x;
    red[t] = ((const float*)(ws + WSO_SLOTS))[t];
    __syncthreads();
    for (int m = 128; m > 0; m >>= 1) {
        if (t < m) red[t] += red[t + m];
        __syncthreads();
    }
    if (t == 0) {
        float m = red[0] / 4194304.0f;
        out_loss[0] = m + m;
    }
}

extern "C" void kernel_launch(void* const* d_in, const int* in_sizes, int n_in,
                              void* d_out, int out_size, void* d_ws, size_t ws_size,
                              hipStream_t stream) {
    const float* x  = (const float*)d_in[0];   // [16,4096,64]
    const float* cb = (const float*)d_in[1];   // [64,1024]
    const float* cf = (const float*)d_in[2];   // [1024]

    float* out      = (float*)d_out;
    float* out_xq   = out;                     // 4,194,304 floats
    float* out_idx  = out + 4194304;           // 65,536
    float* out_loss = out + 4194304 + 65536;   // 1
    float* out_freq = out_loss + 1;            // 1024

    char* ws = (char*)d_ws;                    // 8,256 bytes used

    char*           cbt   = (char*)d_out;                               // 262,144 B
    float*          cbT   = (float*)((char*)d_out + 262144);            // 262,144 B
    unsigned short* list  = (unsigned short*)((char*)d_out + 524288);   // 131,072 B
    float*          parts = (float*)((char*)d_out + 524288);            // 32x4KB (reuses list)

    vq_prep    <<<4,    256, 0, stream>>>(cb, ws, cbt, cbT);
    vq_mfma    <<<1024, 256, 0, stream>>>(x, cbt, ws, list, out_idx);
    vq_refine  <<<4096, 256, 0, stream>>>(x, cb, ws, list, out_idx);
    vq_hist    <<<32,   256, 0, stream>>>(out_idx, parts);
    vq_freq    <<<4,    256, 0, stream>>>(cf, parts, out_freq);
    vq_epi_main<<<2016, 256, 0, stream>>>(x, cbT, out_idx, out_xq, ws);
    vq_epi_tail<<<16,   256, 0, stream>>>(x, cb, out_idx, out_xq, ws);
    vq_loss    <<<1,    256, 0, stream>>>(ws, out_loss);
}

// Round 19
// 81.291 us; speedup vs baseline: 1.1848x; 1.1848x over previous
//
#include <hip/hip_runtime.h>

#define DIM 64
#define NCODE 1024

typedef __attribute__((ext_vector_type(8))) short bf16x8;
typedef __attribute__((ext_vector_type(4))) float f32x4;

// ---- small ws (8.3 KB) ----
#define WSO_SLOTS 0        // float[256] loss slots
#define WSO_COUNT 4100     // int
#define WSO_MAX4  4112     // float[4]
#define WSO_CBN   4160     // float[1024]

// ---- big scratch in d_out's out_xq region ----
// cbt @0 (262144) | cbT @262144 (262144) | list @524288 (131072, reused as hist partials)
// minpack (u64[65536]) @655360 (524288)
// Order: prep -> mfma -> refine -> unpack -> hist -> freq -> E1 -> E2 -> loss.

__device__ __forceinline__ unsigned short f2bf(float f) {
    unsigned u = __float_as_uint(f);
    unsigned r = (u + 0x7FFFu + ((u >> 16) & 1u)) >> 16;   // RNE
    return (unsigned short)r;
}

__device__ __forceinline__ void gload16(const void* g, void* l) {
    __builtin_amdgcn_global_load_lds(
        (const __attribute__((address_space(1))) unsigned int*)g,
        (__attribute__((address_space(3))) unsigned int*)l, 16, 0, 0);
}

__device__ __forceinline__ unsigned fkey(float f) {   // monotone float->uint
    unsigned b = __float_as_uint(f);
    return (b & 0x80000000u) ? ~b : (b | 0x80000000u);
}

// ---- kernel 0: prep (4 x 256) ----
__global__ __launch_bounds__(256) void vq_prep(const float* __restrict__ cb,
                                               char* __restrict__ ws,
                                               char* __restrict__ cbt,
                                               float* __restrict__ cbT) {
    __shared__ float red[256];
    const int t = threadIdx.x;
    const int k = blockIdx.x * 256 + t;

    float cv[64];
#pragma unroll
    for (int d = 0; d < DIM; ++d) cv[d] = cb[d * NCODE + k];

    float s = 0.f;
#pragma unroll
    for (int d = 0; d < DIM; ++d) s = fmaf(cv[d], cv[d], s);

    ((float*)(ws + WSO_CBN))[k] = s;
    if (blockIdx.x == 0) ((float*)(ws + WSO_SLOTS))[t] = 0.f;

    unsigned short hi[64], lo[64];
#pragma unroll
    for (int d = 0; d < DIM; ++d) {
        unsigned short h = f2bf(cv[d]);
        float hf = __uint_as_float(((unsigned)h) << 16);
        hi[d] = h;
        lo[d] = f2bf(cv[d] - hf);
    }

    const int c = k >> 6, cc = k & 63, wv = cc >> 4, col = cc & 15;
    char* base = cbt + (size_t)(c * 4 + wv) * 4096;
#pragma unroll
    for (int g = 0; g < 4; ++g) {
        bf16x8 h0v, h1v, l0v, l1v;
#pragma unroll
        for (int e = 0; e < 8; ++e) {
            h0v[e] = (short)hi[g * 8 + e];
            h1v[e] = (short)hi[32 + g * 8 + e];
            l0v[e] = (short)lo[g * 8 + e];
            l1v[e] = (short)lo[32 + g * 8 + e];
        }
        const int off = (g * 16 + col) * 16;
        *(bf16x8*)(base + off)        = h0v;
        *(bf16x8*)(base + 1024 + off) = h1v;
        *(bf16x8*)(base + 2048 + off) = l0v;
        *(bf16x8*)(base + 3072 + off) = l1v;
    }

#pragma unroll
    for (int j = 0; j < 16; ++j) {
        float4 v = {cv[4 * j], cv[4 * j + 1], cv[4 * j + 2], cv[4 * j + 3]};
        *(float4*)(cbT + (size_t)k * 64 + 4 * j) = v;
    }

    red[t] = s;
    __syncthreads();
    for (int m = 128; m > 0; m >>= 1) {
        if (t < m) red[t] = fmaxf(red[t], red[t + m]);
        __syncthreads();
    }
    if (t == 0) {
        ((float*)(ws + WSO_MAX4))[blockIdx.x] = red[0];
        if (blockIdx.x == 0) *(int*)(ws + WSO_COUNT) = 0;
    }
}

// ---- kernel 1: MFMA distances (R16/R17 verbatim + minpack init at append) ----
__global__ __launch_bounds__(256, 3) void vq_mfma(const float* __restrict__ x,
                                                  const char* __restrict__ cbt,
                                                  char* __restrict__ ws,
                                                  unsigned short* __restrict__ list,
                                                  unsigned long long* __restrict__ minpack,
                                                  float* __restrict__ out_idx) {
    __shared__ __align__(16) char sm[20736];
    char*  bX    = sm;
    float* cbn_s = (float*)(sm + 16384);
    float* xx_s  = (float*)(sm + 20480);
    float* R1    = (float*)sm;
    float* R2v   = R1 + 128;
    int*   RIv   = (int*)(R2v + 128);
    int*   cntL  = (int*)(sm + 8192);

    const int t = threadIdx.x, w = t >> 6, lane = t & 63;
    const int rh = w & 1, ct = w >> 1;
    const int r0 = blockIdx.x * 64;

    const float* mb4 = (const float*)(ws + WSO_MAX4);
    const float maxcbn = fmaxf(fmaxf(mb4[0], mb4[1]), fmaxf(mb4[2], mb4[3]));

    gload16((const char*)(ws + WSO_CBN) + ((size_t)w * 64 + lane) * 16, (char*)cbn_s + w * 1024);

    {
        const int row = t >> 2, q = t & 3;
        const float4* xp = (const float4*)(x + (size_t)(r0 + row) * DIM + q * 16);
        float4 v0 = xp[0], v1 = xp[1], v2 = xp[2], v3 = xp[3];
        float p = 0.f;
        p = fmaf(v0.x, v0.x, p); p = fmaf(v0.y, v0.y, p); p = fmaf(v0.z, v0.z, p); p = fmaf(v0.w, v0.w, p);
        p = fmaf(v1.x, v1.x, p); p = fmaf(v1.y, v1.y, p); p = fmaf(v1.z, v1.z, p); p = fmaf(v1.w, v1.w, p);
        p = fmaf(v2.x, v2.x, p); p = fmaf(v2.y, v2.y, p); p = fmaf(v2.z, v2.z, p); p = fmaf(v2.w, v2.w, p);
        p = fmaf(v3.x, v3.x, p); p = fmaf(v3.y, v3.y, p); p = fmaf(v3.z, v3.z, p); p = fmaf(v3.w, v3.w, p);
        p += __shfl_xor(p, 1);
        p += __shfl_xor(p, 2);
        if (q == 0) xx_s[row] = p;

        float hv[16] = {v0.x, v0.y, v0.z, v0.w, v1.x, v1.y, v1.z, v1.w,
                        v2.x, v2.y, v2.z, v2.w, v3.x, v3.y, v3.z, v3.w};
        bf16x8 ph[2], pl[2];
#pragma unroll
        for (int h = 0; h < 2; ++h)
#pragma unroll
            for (int e = 0; e < 8; ++e) {
                float v = hv[h * 8 + e];
                unsigned short hb = f2bf(v);
                float hf = __uint_as_float(((unsigned)hb) << 16);
                ph[h][e] = (short)hb;
                pl[h][e] = (short)f2bf(v - hf);
            }
        const int sw = row & 7;
        char* base = bX + row * 256;
#pragma unroll
        for (int h = 0; h < 2; ++h) {
            int s3 = (2 * q + h) ^ sw;
            *(bf16x8*)(base + (s3 & 7) * 16)        = ph[h];
            *(bf16x8*)(base + (8 | (s3 & 7)) * 16)  = pl[h];
        }
    }
    __syncthreads();

    bf16x8 afh[2][2], afl[2][2];
#pragma unroll
    for (int rt = 0; rt < 2; ++rt)
#pragma unroll
        for (int kt = 0; kt < 2; ++kt) {
            int row = rh * 32 + rt * 16 + (lane & 15);
            int s3 = ((kt * 4 + (lane >> 4)) ^ (row & 7)) & 7;
            afh[rt][kt] = *(const bf16x8*)(bX + row * 256 + s3 * 16);
            afl[rt][kt] = *(const bf16x8*)(bX + row * 256 + (8 | s3) * 16);
        }

    const int cl = ct * 16 + (lane & 15);

    float m1[8], m2[8];
    int   mi[8];
#pragma unroll
    for (int s = 0; s < 8; ++s) { m1[s] = 3.4e38f; m2[s] = 3.4e38f; mi[s] = 0; }

    const char* pc = cbt + (size_t)ct * 4096 + (size_t)lane * 16;

    bf16x8 bh0 = *(const bf16x8*)(pc);
    bf16x8 bh1 = *(const bf16x8*)(pc + 1024);
    bf16x8 bl0 = *(const bf16x8*)(pc + 2048);
    bf16x8 bl1 = *(const bf16x8*)(pc + 3072);

#pragma unroll 1
    for (int c2 = 0; c2 < 32; ++c2) {
        const char* np = pc + 8192;
        bf16x8 nh0 = *(const bf16x8*)(np);
        bf16x8 nh1 = *(const bf16x8*)(np + 1024);
        bf16x8 nl0 = *(const bf16x8*)(np + 2048);
        bf16x8 nl1 = *(const bf16x8*)(np + 3072);

        const int kg = c2 * 32 + cl;
        const float cbnv = cbn_s[kg];

#pragma unroll
        for (int rt = 0; rt < 2; ++rt) {
            f32x4 z = {0.f, 0.f, 0.f, 0.f};
            z = __builtin_amdgcn_mfma_f32_16x16x32_bf16(afh[rt][0], bh0, z, 0, 0, 0);
            z = __builtin_amdgcn_mfma_f32_16x16x32_bf16(afh[rt][1], bh1, z, 0, 0, 0);
            z = __builtin_amdgcn_mfma_f32_16x16x32_bf16(afl[rt][0], bh0, z, 0, 0, 0);
            z = __builtin_amdgcn_mfma_f32_16x16x32_bf16(afl[rt][1], bh1, z, 0, 0, 0);
            z = __builtin_amdgcn_mfma_f32_16x16x32_bf16(afh[rt][0], bl0, z, 0, 0, 0);
            z = __builtin_amdgcn_mfma_f32_16x16x32_bf16(afh[rt][1], bl1, z, 0, 0, 0);
#pragma unroll
            for (int v = 0; v < 4; ++v) {
                const int s = rt * 4 + v;
                float dd = fmaf(-2.f, z[v], cbnv);
                bool lt = dd < m1[s];
                m2[s] = fminf(m2[s], fmaxf(m1[s], dd));
                m1[s] = fminf(m1[s], dd);
                mi[s] = lt ? kg : mi[s];
            }
        }
        pc = np;
        bh0 = nh0; bh1 = nh1; bl0 = nl0; bl1 = nl1;
    }

#pragma unroll
    for (int m = 1; m <= 8; m <<= 1) {
#pragma unroll
        for (int s = 0; s < 8; ++s) {
            float o1 = __shfl_xor(m1[s], m);
            float o2 = __shfl_xor(m2[s], m);
            int   oi = __shfl_xor(mi[s], m);
            float nm2 = fminf(fminf(m2[s], o2), fmaxf(m1[s], o1));
            bool tk = (o1 < m1[s]) || (o1 == m1[s] && oi < mi[s]);
            m1[s] = fminf(m1[s], o1);
            mi[s] = tk ? oi : mi[s];
            m2[s] = nm2;
        }
    }
    __syncthreads();
    if ((lane & 15) == 0) {
        const int gq = lane >> 4;
#pragma unroll
        for (int s = 0; s < 8; ++s) {
            const int row = rh * 32 + (s >> 2) * 16 + gq * 4 + (s & 3);
            R1[row * 2 + ct]  = m1[s];
            R2v[row * 2 + ct] = m2[s];
            RIv[row * 2 + ct] = mi[s];
        }
    }
    __syncthreads();

    bool flag = false;
    int  rr = 0;
    if (t < 128) {
        const int row = t >> 1, q = t & 1;
        float a1 = R1[row * 2 + q];
        float A2 = R2v[row * 2 + q];
        int   ai = RIv[row * 2 + q];
        {
            float o1 = __shfl_xor(a1, 1);
            float o2 = __shfl_xor(A2, 1);
            int   oi = __shfl_xor(ai, 1);
            float nm2 = fminf(fminf(A2, o2), fmaxf(a1, o1));
            bool tk = (o1 < a1) || (o1 == a1 && oi < ai);
            a1 = fminf(a1, o1);
            ai = tk ? oi : ai;
            A2 = nm2;
        }
        if (q == 0) {
            const int r = r0 + row;
            out_idx[r] = (float)ai;
            const float Bv = 1.5e-4f * sqrtf(xx_s[row] * maxcbn) + 2e-3f;
            flag = (A2 - a1 <= 2.f * Bv);
            rr = r;
        }
    }
    unsigned long long mk = __ballot(flag);
    const int wcnt = __popcll(mk);
    if (lane == 0) cntL[w] = wcnt;
    __syncthreads();
    if (t == 0) {
        int c0 = cntL[0], c1 = cntL[1], c2 = cntL[2], c3 = cntL[3];
        int tot = c0 + c1 + c2 + c3;
        int base = 0;
        if (tot) base = atomicAdd((int*)(ws + WSO_COUNT), tot);
        cntL[0] = base;
        cntL[1] = base + c0;
        cntL[2] = base + c0 + c1;
        cntL[3] = base + c0 + c1 + c2;
    }
    __syncthreads();
    if (flag) {
        const int off = __popcll(mk & ((1ull << lane) - 1ull));
        const int pos = cntL[w] + off;
        list[pos] = (unsigned short)rr;
        minpack[pos] = ~0ull;                 // init for refine's atomicMin
    }
}

// ---- kernel 2: refine v6 — item = (list row, code quarter); 4N items over 8192 waves ----
// Per item: one coalesced x-row load + shfl broadcasts (no LDS/barriers), scan 256
// codes with v3's exact arithmetic (bit-identical across quarters), packed atomicMin.
__global__ __launch_bounds__(256) void vq_refine(const float* __restrict__ x,
                                                 const float* __restrict__ cb,
                                                 const char* __restrict__ ws,
                                                 const unsigned short* __restrict__ list,
                                                 unsigned long long* __restrict__ minpack) {
    const int N = *(const int*)(ws + WSO_COUNT);
    const float* cbn = (const float*)(ws + WSO_CBN);
    const int t = threadIdx.x, w = t >> 6, lane = t & 63;
    const int gw = blockIdx.x * 4 + w;          // global wave id, 8192 total
    const int items = N * 4;

    for (int item = gw; item < items; item += 8192) {
        const int i  = item >> 2;
        const int qq = item & 3;
        const int r  = (int)list[i];

        const float xv = x[(size_t)r * DIM + lane];   // coalesced 256B
        float p = xv * xv;
#pragma unroll
        for (int m = 1; m < 64; m <<= 1) p += __shfl_xor(p, m);
        const float xx = p;                           // bit-identical per quarter

        float bd = 3.4e38f;
        int   bk = 0;
#pragma unroll
        for (int b = 0; b < 4; ++b) {
            const int kb = qq * 256 + b * 64;
            const float* cp = cb + kb + lane;
            float d0 = 0.f, d1 = 0.f, d2 = 0.f, d3 = 0.f;
#pragma unroll
            for (int j = 0; j < 16; ++j) {
                d0 = fmaf(__shfl(xv, 4 * j + 0), cp[(4 * j + 0) * NCODE], d0);
                d1 = fmaf(__shfl(xv, 4 * j + 1), cp[(4 * j + 1) * NCODE], d1);
                d2 = fmaf(__shfl(xv, 4 * j + 2), cp[(4 * j + 2) * NCODE], d2);
                d3 = fmaf(__shfl(xv, 4 * j + 3), cp[(4 * j + 3) * NCODE], d3);
            }
            const float dot = (d0 + d1) + (d2 + d3);
            const float dist = fmaf(-2.f, dot, xx) + cbn[kb + lane];
            const int k = kb + lane;
            if (dist < bd) { bd = dist; bk = k; }     // per-lane k ascending
        }
#pragma unroll
        for (int m = 1; m < 64; m <<= 1) {
            float od = __shfl_xor(bd, m);
            int   ok = __shfl_xor(bk, m);
            if (od < bd || (od == bd && ok < bk)) { bd = od; bk = ok; }
        }
        if (lane == 0) {
            unsigned long long pk = ((unsigned long long)fkey(bd) << 32) | (unsigned)bk;
            atomicMin(&minpack[i], pk);               // ties -> lowest k (np.argmin)
        }
    }
}

// ---- kernel 2a: unpack refined argmins ----
__global__ __launch_bounds__(256) void vq_unpack(const char* __restrict__ ws,
                                                 const unsigned short* __restrict__ list,
                                                 const unsigned long long* __restrict__ minpack,
                                                 float* __restrict__ out_idx) {
    const int N = *(const int*)(ws + WSO_COUNT);
    const int i = blockIdx.x * 256 + threadIdx.x;
    if (i < N) out_idx[(int)list[i]] = (float)(unsigned)(minpack[i] & 0xFFFFFFFFull);
}

// ---- kernel 2b: atomic-free histogram (R17 verbatim) ----
__global__ __launch_bounds__(256) void vq_hist(const float* __restrict__ idx_f,
                                               float* __restrict__ partials) {
    __shared__ int lh[1024];
    const int t = threadIdx.x;
    lh[t] = 0; lh[t + 256] = 0; lh[t + 512] = 0; lh[t + 768] = 0;
    __syncthreads();
    const int base = blockIdx.x * 2048;
#pragma unroll
    for (int i = 0; i < 8; ++i) {
        int k = (int)idx_f[base + i * 256 + t];
        atomicAdd(&lh[k], 1);
    }
    __syncthreads();
    float* P = partials + (size_t)blockIdx.x * 1024;
    P[t]       = (float)lh[t];
    P[t + 256] = (float)lh[t + 256];
    P[t + 512] = (float)lh[t + 512];
    P[t + 768] = (float)lh[t + 768];
}

// ---- kernel 2c: freq (R17 verbatim) ----
__global__ __launch_bounds__(256) void vq_freq(const float* __restrict__ cf,
                                               const float* __restrict__ partials,
                                               float* __restrict__ out_freq) {
    const int k = blockIdx.x * 256 + threadIdx.x;
    float s = 0.f;
#pragma unroll
    for (int b = 0; b < 32; ++b) s += partials[(size_t)b * 1024 + k];
    out_freq[k] = 0.95f * cf[k] + 0.05f * s;
}

// ---- kernel 3a: epilogue E1 (R17 verbatim) ----
__global__ __launch_bounds__(256) void vq_epi_main(const float* __restrict__ x,
                                                   const float* __restrict__ cbT,
                                                   const float* __restrict__ idx_f,
                                                   float* __restrict__ out_xq,
                                                   char* __restrict__ ws) {
    __shared__ float lred[4];
    const int t = threadIdx.x;
    const int r_lin = blockIdx.x * 32 + (t >> 3);
    const int r = (r_lin < 1024) ? r_lin : r_lin + 1024;
    const int q8 = t & 7;
    const int k = (int)idx_f[r];

    const float4* cp = (const float4*)(cbT + (size_t)k * 64 + q8 * 8);
    const float4* xp = (const float4*)(x + (size_t)r * DIM + q8 * 8);
    float4* op = (float4*)(out_xq + (size_t)r * DIM + q8 * 8);

    float4 c0 = cp[0], c1 = cp[1];
    float4 x0 = xp[0], x1 = xp[1];
    float e0 = c0.x - x0.x, e1 = c0.y - x0.y, e2 = c0.z - x0.z, e3 = c0.w - x0.w;
    float e4 = c1.x - x1.x, e5 = c1.y - x1.y, e6 = c1.z - x1.z, e7 = c1.w - x1.w;
    float4 o0, o1;
    o0.x = x0.x + e0; o0.y = x0.y + e1; o0.z = x0.z + e2; o0.w = x0.w + e3;
    o1.x = x1.x + e4; o1.y = x1.y + e5; o1.z = x1.z + e6; o1.w = x1.w + e7;
    op[0] = o0; op[1] = o1;

    float lsum = 0.f;
    lsum = fmaf(e0, e0, lsum); lsum = fmaf(e1, e1, lsum);
    lsum = fmaf(e2, e2, lsum); lsum = fmaf(e3, e3, lsum);
    lsum = fmaf(e4, e4, lsum); lsum = fmaf(e5, e5, lsum);
    lsum = fmaf(e6, e6, lsum); lsum = fmaf(e7, e7, lsum);

#pragma unroll
    for (int off = 1; off < 64; off <<= 1) lsum += __shfl_xor(lsum, off);
    if ((t & 63) == 0) lred[t >> 6] = lsum;
    __syncthreads();
    if (t == 0)
        atomicAdd((float*)(ws + WSO_SLOTS) + (blockIdx.x & 255),
                  (lred[0] + lred[1]) + (lred[2] + lred[3]));
}

// ---- kernel 3b: epilogue E2 (R17 verbatim) ----
__global__ __launch_bounds__(256) void vq_epi_tail(const float* __restrict__ x,
                                                   const float* __restrict__ cb,
                                                   const float* __restrict__ idx_f,
                                                   float* __restrict__ out_xq,
                                                   char* __restrict__ ws) {
    __shared__ float lred[4];
    const int t = threadIdx.x;
    const int row = 1024 + blockIdx.x * 64 + (t >> 2), q = t & 3;
    const int k = (int)idx_f[row];
    const float4* xp = (const float4*)(x + (size_t)row * DIM + q * 16);
    float4* op = (float4*)(out_xq + (size_t)row * DIM + q * 16);
    float lsum = 0.f;
#pragma unroll
    for (int j = 0; j < 4; ++j) {
        float4 xv = xp[j];
        const int d0 = q * 16 + 4 * j;
        float q0 = cb[(d0 + 0) * NCODE + k];
        float q1 = cb[(d0 + 1) * NCODE + k];
        float q2 = cb[(d0 + 2) * NCODE + k];
        float q3 = cb[(d0 + 3) * NCODE + k];
        float e0 = q0 - xv.x, e1 = q1 - xv.y, e2 = q2 - xv.z, e3 = q3 - xv.w;
        float4 o;
        o.x = xv.x + e0; o.y = xv.y + e1; o.z = xv.z + e2; o.w = xv.w + e3;
        op[j] = o;
        lsum = fmaf(e0, e0, lsum); lsum = fmaf(e1, e1, lsum);
        lsum = fmaf(e2, e2, lsum); lsum = fmaf(e3, e3, lsum);
    }
#pragma unroll
    for (int off = 1; off < 64; off <<= 1) lsum += __shfl_xor(lsum, off);
    if ((t & 63) == 0) lred[t >> 6] = lsum;
    __syncthreads();
    if (t == 0)
        atomicAdd((float*)(ws + WSO_SLOTS) + blockIdx.x,
                  (lred[0] + lred[1]) + (lred[2] + lred[3]));
}

// ---- kernel 4: loss finalize (R17 verbatim) ----
__global__ __launch_bounds__(256) void vq_loss(const char* __restrict__ ws,
                                               float* __restrict__ out_loss) {
    __shared__ float red[256];
    const int t = threadIdx.x;
    red[t] = ((const float*)(ws + WSO_SLOTS))[t];
    __syncthreads();
    for (int m = 128; m > 0; m >>= 1) {
        if (t < m) red[t] += red[t + m];
        __syncthreads();
    }
    if (t == 0) {
        float m = red[0] / 4194304.0f;
        out_loss[0] = m + m;
    }
}

extern "C" void kernel_launch(void* const* d_in, const int* in_sizes, int n_in,
                              void* d_out, int out_size, void* d_ws, size_t ws_size,
                              hipStream_t stream) {
    const float* x  = (const float*)d_in[0];   // [16,4096,64]
    const float* cb = (const float*)d_in[1];   // [64,1024]
    const float* cf = (const float*)d_in[2];   // [1024]

    float* out      = (float*)d_out;
    float* out_xq   = out;                     // 4,194,304 floats
    float* out_idx  = out + 4194304;           // 65,536
    float* out_loss = out + 4194304 + 65536;   // 1
    float* out_freq = out_loss + 1;            // 1024

    char* ws = (char*)d_ws;                    // 8,256 bytes used

    char*               cbt     = (char*)d_out;                                // 262,144 B
    float*              cbT     = (float*)((char*)d_out + 262144);             // 262,144 B
    unsigned short*     list    = (unsigned short*)((char*)d_out + 524288);    // 131,072 B
    float*              parts   = (float*)((char*)d_out + 524288);             // reuses list post-refine
    unsigned long long* minpack = (unsigned long long*)((char*)d_out + 655360); // 524,288 B

    vq_prep    <<<4,    256, 0, stream>>>(cb, ws, cbt, cbT);
    vq_mfma    <<<1024, 256, 0, stream>>>(x, cbt, ws, list, minpack, out_idx);
    vq_refine  <<<2048, 256, 0, stream>>>(x, cb, ws, list, minpack);
    vq_unpack  <<<256,  256, 0, stream>>>(ws, list, minpack, out_idx);
    vq_hist    <<<32,   256, 0, stream>>>(out_idx, parts);
    vq_freq    <<<4,    256, 0, stream>>>(cf, parts, out_freq);
    vq_epi_main<<<2016, 256, 0, stream>>>(x, cbT, out_idx, out_xq, ws);
    vq_epi_tail<<<16,   256, 0, stream>>>(x, cb, out_idx, out_xq, ws);
    vq_loss    <<<1,    256, 0, stream>>>(ws, out_loss);
}